// Round 3
// baseline (407.273 us; speedup 1.0000x reference)
//
#include <hip/hip_runtime.h>
#include <cmath>

#define LIF_L 2048
#define LIF_F 256
#define LIF_B 64
#define LIF_BF (LIF_B * LIF_F)
#define TT 128              // timesteps per tile
#define NT (LIF_L / TT)     // 16 tiles
#define W4 (TT / 4)         // 32 float4 per chain-row per tile
#define S4 (W4 + 1)         // 33 float4 LDS row stride -> conflict-free b128 both ways

// One wave per block, 64 chains per block, 256 blocks = 1 wave/CU.
// LDS transpose stages I (in) and v_pre (out); z and s are recomputed from
// v_pre in the coalesced store phase, halving output LDS traffic.
__global__ __launch_bounds__(64, 1) void lif_scan_kernel(
    const float* __restrict__ I, const float* __restrict__ raw_tau,
    const float* __restrict__ thr_p, float* __restrict__ out) {
#pragma clang fp contract(off)
  __shared__ float4 ldsI[64 * S4];  // 33.8 KB
  __shared__ float4 ldsV[64 * S4];  // 33.8 KB

  const int lane = threadIdx.x;
  const int cbase = blockIdx.x * 64;
  const int q = lane >> 4;   // row sub-index 0..3
  const int m = lane & 15;   // float4 column 0..15 (and +16)

  // alpha in double = correctly-rounded fp32 target (matches numpy semantics)
  const int f = (cbase + lane) & (LIF_F - 1);
  const double rt = (double)raw_tau[f];
  const double sp = (rt > 0.0) ? (rt + log1p(exp(-rt))) : log1p(exp(rt));
  const float alpha = (float)exp(-1.0 / (sp + 1e-4));
  const float oma = 1.0f - alpha;
  const float thr = thr_p[0];
  const float beta = 15.0f;

  const float4* __restrict__ Ip = (const float4*)I;
  float4* __restrict__ Zp = (float4*)out;
  float4* __restrict__ Sp = (float4*)(out + (size_t)LIF_BF * LIF_L);

  float v = 0.0f;
  float4 inbuf[32];  // 128 VGPRs: one full tile staged in registers

  // prologue: issue tile-0 loads (fully coalesced: 16 lanes x 16B per row)
#pragma unroll
  for (int k = 0; k < 16; ++k) {
    const size_t rb = (size_t)(cbase + 4 * k + q) * (LIF_L / 4);
    inbuf[2 * k] = Ip[rb + m];
    inbuf[2 * k + 1] = Ip[rb + m + 16];
  }

  for (int tile = 0; tile < NT; ++tile) {
    // phase 1: stage current tile regs -> LDS (b128, conflict-free)
#pragma unroll
    for (int k = 0; k < 16; ++k) {
      const int row = 4 * k + q;
      ldsI[row * S4 + m] = inbuf[2 * k];
      ldsI[row * S4 + m + 16] = inbuf[2 * k + 1];
    }
    // phase 2: prefetch next tile (32 dwordx4 in flight through compute+store)
    if (tile + 1 < NT) {
#pragma unroll
      for (int k = 0; k < 16; ++k) {
        const size_t rb =
            (size_t)(cbase + 4 * k + q) * (LIF_L / 4) + (tile + 1) * W4;
        inbuf[2 * k] = Ip[rb + m];
        inbuf[2 * k + 1] = Ip[rb + m + 16];
      }
    }
    // single wave per block: same-wave DS ops are in-order; scheduling fence
    // only (no vmcnt(0) drain like __syncthreads would force).
    __builtin_amdgcn_wave_barrier();

    // phase 3: sequential scan, lane = chain; b128 reads/writes, store v_pre
    const float4* rI = &ldsI[lane * S4];
    float4* rV = &ldsV[lane * S4];
#pragma unroll 8
    for (int u = 0; u < W4; ++u) {
      const float4 in = rI[u];
      float4 vp;
      // contraction OFF: mul, mul, add rounded separately (matches numpy)
      vp.x = alpha * v + oma * in.x;
      v = (vp.x >= thr) ? 0.0f : vp.x;   // == v_pre*(1-s) bit-exactly
      vp.y = alpha * v + oma * in.y;
      v = (vp.y >= thr) ? 0.0f : vp.y;
      vp.z = alpha * v + oma * in.z;
      v = (vp.z >= thr) ? 0.0f : vp.z;
      vp.w = alpha * v + oma * in.w;
      v = (vp.w >= thr) ? 0.0f : vp.w;
      rV[u] = vp;
    }
    __builtin_amdgcn_wave_barrier();

    // phase 4: coalesced stores; z and s recomputed from v_pre in registers
#pragma unroll
    for (int k = 0; k < 16; ++k) {
      const int row = 4 * k + q;
      const size_t rb = (size_t)(cbase + row) * (LIF_L / 4) + tile * W4;
#pragma unroll
      for (int h = 0; h < 2; ++h) {
        const int col = m + 16 * h;
        const float4 vp = ldsV[row * S4 + col];
        float4 z, s;
        z.x = beta * (vp.x - thr); s.x = (vp.x >= thr) ? 1.0f : 0.0f;
        z.y = beta * (vp.y - thr); s.y = (vp.y >= thr) ? 1.0f : 0.0f;
        z.z = beta * (vp.z - thr); s.z = (vp.z >= thr) ? 1.0f : 0.0f;
        z.w = beta * (vp.w - thr); s.w = (vp.w >= thr) ? 1.0f : 0.0f;
        Zp[rb + col] = z;
        Sp[rb + col] = s;
      }
    }
    __builtin_amdgcn_wave_barrier();  // WAR fence before next tile's LDS reuse
  }
}

extern "C" void kernel_launch(void* const* d_in, const int* in_sizes, int n_in,
                              void* d_out, int out_size, void* d_ws,
                              size_t ws_size, hipStream_t stream) {
  const float* I = (const float*)d_in[0];
  const float* raw_tau = (const float*)d_in[1];
  const float* thr = (const float*)d_in[2];
  float* out = (float*)d_out;
  dim3 grid(LIF_BF / 64), block(64);
  lif_scan_kernel<<<grid, block, 0, stream>>>(I, raw_tau, thr, out);
}